// Round 12
// baseline (351.884 us; speedup 1.0000x reference)
//
#include <hip/hip_runtime.h>
#include <cstdint>
#include <cstddef>

#define NI   256
#define QKC  32
#define BS   4
#define NPIX 4096   // 64*64
#define LOG2E 1.4426950408889634f

typedef __bf16 bf16x8 __attribute__((ext_vector_type(8)));
typedef __bf16 bf16x4 __attribute__((ext_vector_type(4)));
typedef float  f32x16 __attribute__((ext_vector_type(16)));

__device__ inline f32x16 zero16() {
    f32x16 z;
    #pragma unroll
    for (int i = 0; i < 16; ++i) z[i] = 0.f;
    return z;
}

// ---------------- Kernel 0: W -> fragment-packed bf16 (+ flag zeroing) ------
__global__ __launch_bounds__(256) void wconv_pack(
    const float* __restrict__ wq, const float* __restrict__ wk,
    const float* __restrict__ wv, __bf16* __restrict__ wpk,
    int* __restrict__ flags)
{
    if (blockIdx.x == 0) flags[threadIdx.x] = 0;   // 256 combine flags

    int f = blockIdx.x * 256 + threadIdx.x;          // 0..10239
    int otl = f >> 10, rem = f & 1023;
    int kk = rem >> 6, h = (rem >> 5) & 1, l31 = rem & 31;
    int och = otl * 32 + l31, c0 = kk * 16 + 8 * h;
    const float* src = och < 32 ? wq + och * NI + c0
                     : och < 64 ? wk + (och - 32) * NI + c0
                                : wv + (och - 64) * NI + c0;
    float4 x0 = *(const float4*)src;
    float4 x1 = *(const float4*)(src + 4);
    __align__(16) __bf16 o8[8] = {
        (__bf16)x0.x, (__bf16)x0.y, (__bf16)x0.z, (__bf16)x0.w,
        (__bf16)x1.x, (__bf16)x1.y, (__bf16)x1.z, (__bf16)x1.w};
    *(uint4*)(wpk + (size_t)f * 8) = *(const uint4*)o8;
}

// ---------------- Kernel 1: QKV (round-11 verbatim) ----------
// qpk: [b][kt(128)][kc][h][l31][8]  (single bf16 plane)
// kpk: [b][kt(128)][kc][h][l31][8]
// vpk: [b][kt(128)][kc][hh][c'(256)][8]
__global__ __launch_bounds__(256) void qkv_mfma(
    const float* __restrict__ x, const __bf16* __restrict__ wpk,
    const float* __restrict__ bq, const float* __restrict__ bk,
    const float* __restrict__ bv,
    __bf16* __restrict__ qpk, __bf16* __restrict__ kpk, __bf16* __restrict__ vpk)
{
    __shared__ __align__(16) __bf16 xT[32][264];   // also reused as vT
    __shared__ float bls[320];

    const int t = threadIdx.x, w = t >> 6, lane = t & 63;
    const int l31 = lane & 31, h = lane >> 5;
    const int b = blockIdx.y, n0 = blockIdx.x * 32, kt = blockIdx.x;

    for (int i = t; i < 320; i += 256)
        bls[i] = i < 32 ? bq[i] : i < 64 ? bk[i - 32] : bv[i - 64];

    {   // stage x transposed (32 n x 256 c)
        int n4 = (t & 7) * 4, cb = (t >> 3) * 8;
        float4 xv[8];
        #pragma unroll
        for (int j = 0; j < 8; ++j)
            xv[j] = *(const float4*)(x + ((size_t)(b * NI) + cb + j) * NPIX + n0 + n4);
        #pragma unroll
        for (int i = 0; i < 4; ++i) {
            __align__(16) __bf16 r8[8];
            #pragma unroll
            for (int j = 0; j < 8; ++j) r8[j] = (__bf16)((&xv[j].x)[i]);
            *(uint4*)&xT[n4 + i][cb] = *(const uint4*)r8;
        }
    }
    __syncthreads();

    f32x16 acc[3] = {zero16(), zero16(), zero16()};
    #pragma unroll 4
    for (int kk = 0; kk < 16; ++kk) {
        bf16x8 xf = *(const bf16x8*)&xT[l31][kk * 16 + 8 * h];
        #pragma unroll
        for (int jj = 0; jj < 3; ++jj) {
            int otl = w + 4 * jj;
            if (otl < 10) {
                bf16x8 wf = *(const bf16x8*)(wpk + (size_t)((otl * 16 + kk) * 64 + 32 * h + l31) * 8);
                acc[jj] = __builtin_amdgcn_mfma_f32_32x32x16_bf16(wf, xf, acc[jj], 0, 0, 0);
            }
        }
    }
    __syncthreads();   // xT reads done; reuse as vT

    __bf16 (*vT)[264] = xT;
    #pragma unroll
    for (int jj = 0; jj < 3; ++jj) {
        int otl = w + 4 * jj;
        if (otl >= 2 && otl < 10) {
            #pragma unroll
            for (int qd = 0; qd < 4; ++qd) {
                int c0v = (otl - 2) * 32 + 8 * qd + 4 * h;
                __align__(8) __bf16 q4[4];
                #pragma unroll
                for (int i = 0; i < 4; ++i)
                    q4[i] = (__bf16)(acc[jj][4 * qd + i] + bls[64 + c0v + i]);
                *(uint2*)&vT[l31][c0v] = *(const uint2*)q4;
            }
        }
    }
    #pragma unroll
    for (int jj = 0; jj < 3; ++jj) {
        int otl = w + 4 * jj;
        if (otl == 0) {        // q: scale by log2e, single bf16 plane
            #pragma unroll
            for (int kc = 0; kc < 2; ++kc) {
                __align__(16) __bf16 hi8[8];
                #pragma unroll
                for (int j = 0; j < 8; ++j) {
                    int r = 8 * kc + j;
                    int och = (r & 3) + 8 * (r >> 2) + 4 * h;
                    hi8[j] = (__bf16)((acc[jj][r] + bls[och]) * LOG2E);
                }
                size_t base = ((((size_t)(b * 128 + kt) * 2 + 0) * 2 + kc) * 2 + h) * 32 + l31;
                *(uint4*)(qpk + base * 8) = *(const uint4*)hi8;
            }
        } else if (otl == 1) { // k
            #pragma unroll
            for (int kc = 0; kc < 2; ++kc) {
                __align__(16) __bf16 k8[8];
                #pragma unroll
                for (int j = 0; j < 8; ++j) {
                    int r = 8 * kc + j;
                    int och = (r & 3) + 8 * (r >> 2) + 4 * h;
                    k8[j] = (__bf16)(acc[jj][r] + bls[32 + och]);
                }
                size_t base = (((size_t)(b * 128 + kt) * 2 + kc) * 2 + h) * 32 + l31;
                *(uint4*)(kpk + base * 8) = *(const uint4*)k8;
            }
        }
    }
    __syncthreads();   // vT complete

    #pragma unroll
    for (int kc = 0; kc < 2; ++kc)
        #pragma unroll
        for (int hh = 0; hh < 2; ++hh) {
            __align__(16) __bf16 f8[8];
            #pragma unroll
            for (int j = 0; j < 8; ++j) f8[j] = vT[16 * kc + 8 * hh + j][t];
            size_t base = (((size_t)(b * 128 + kt) * 2 + kc) * 2 + hh) * 256 + t;
            *(uint4*)(vpk + base * 8) = *(const uint4*)f8;
        }
}

// ---------------- Kernel 2: attention + fused last-block combine ------------
// Round-11 main loop verbatim. Epilogue: both ksp blocks write bf16 partials
// (Opart plane ksp + dpart), __threadfence, atomicAdd on a per-(b,ntile)
// flag; the second arriver keeps its own partial in f32 regs, reads the
// partner plane + x + gamma, and writes the final output coalesced via an
// LDS transpose (stage aliases the now-dead pt_f pool, +1-pad rows).
__global__ __launch_bounds__(512, 4) void attn_mfma(
    const __bf16* __restrict__ qpk, const __bf16* __restrict__ kpk,
    const __bf16* __restrict__ vpk,
    __bf16* __restrict__ Opart, float* __restrict__ dpart,
    const float* __restrict__ x, const float* __restrict__ gamma,
    float* __restrict__ out, int* __restrict__ flags)
{
    // pool: max(pt_f 4*2*4*64*8 bf16 = 32768 B, stage 128*65*4 = 33280 B)
    __shared__ __align__(16) unsigned char smem[33280];
    auto pt_f = reinterpret_cast<__bf16 (*)[2][4][64][8]>(smem);
    __shared__ float dwave[8][32];
    __shared__ float dls[64];
    __shared__ int who;

    const int t = threadIdx.x;
    const int b = blockIdx.x & 3, ksp = blockIdx.x >> 2;
    const int n0 = blockIdx.y * 64;
    const int w = t >> 6, lane = t & 63, l31 = lane & 31, h = lane >> 5;
    const int q = w & 3, sr = q & 1, sc = q >> 1, pp = w >> 2;
    const int kt0 = ksp * 64;                 // key-tile base (32-key units)

    // Q fragments for this wave's S n-half (kc halves, single plane)
    const int qt = 2 * blockIdx.y + sr;
    bf16x8 qf[2];
    #pragma unroll
    for (int kc = 0; kc < 2; ++kc)
        qf[kc] = *(const bf16x8*)(qpk +
            (((((size_t)(b * 128 + qt) * 2 + 0) * 2 + kc) * 2 + h) * 32 + l31) * 8);

    auto kload = [&](int ktile, int kc) {
        return *(const bf16x8*)(kpk +
            ((((size_t)(b * 128 + ktile) * 2 + kc) * 2 + h) * 32 + l31) * 8);
    };
    auto vload = [&](int ktile, int kc) {
        return *(const bf16x8*)(vpk +
            ((((size_t)(b * 128 + ktile) * 2 + kc) * 2 + h) * 256 + 32 * w + l31) * 8);
    };

    f32x16 a0 = zero16(), a1 = zero16();
    float dacc = 0.f;

    auto smma = [&](bf16x8 kh0, bf16x8 kh1) {
        f32x16 s = zero16();
        __builtin_amdgcn_s_setprio(1);
        s = __builtin_amdgcn_mfma_f32_32x32x16_bf16(kh0, qf[0], s, 0, 0, 0);
        s = __builtin_amdgcn_mfma_f32_32x32x16_bf16(kh1, qf[1], s, 0, 0, 0);
        __builtin_amdgcn_s_setprio(0);
        return s;
    };

    auto sfin = [&](const f32x16& s, int buf) {
        unsigned xw[8], xs[8];
        #pragma unroll
        for (int i = 0; i < 8; ++i) {
            float e0 = __builtin_amdgcn_exp2f(s[2 * i]);
            float e1 = __builtin_amdgcn_exp2f(s[2 * i + 1]);
            dacc += e0 + e1;
            __align__(4) __bf16 pr[2] = {(__bf16)e0, (__bf16)e1};
            xw[i] = *(const unsigned*)pr;
        }
        #pragma unroll
        for (int i = 0; i < 8; ++i) xs[i] = __shfl_xor(xw[i], 32);
        const bool hi = (h != 0);
        __align__(16) unsigned f0[4], f1[4];
        f0[0] = hi ? xs[2] : xw[0];  f0[1] = hi ? xs[3] : xw[1];
        f0[2] = hi ? xw[2] : xs[0];  f0[3] = hi ? xw[3] : xs[1];
        f1[0] = hi ? xs[6] : xw[4];  f1[1] = hi ? xs[7] : xw[5];
        f1[2] = hi ? xw[6] : xs[4];  f1[3] = hi ? xw[7] : xs[5];
        *(uint4*)&pt_f[buf][sr][2 * sc + 0][lane][0] = *(const uint4*)f0;
        *(uint4*)&pt_f[buf][sr][2 * sc + 1][lane][0] = *(const uint4*)f1;
    };

    auto pvblock = [&](int mt, const bf16x8 (*vf)[2]) {
        const int buf = mt & 3;
        __builtin_amdgcn_s_setprio(1);
        #pragma unroll
        for (int i = 0; i < 2; ++i)
            #pragma unroll
            for (int kc = 0; kc < 2; ++kc) {
                const int s2 = 2 * i + kc;
                bf16x8 pa0 = *(const bf16x8*)&pt_f[buf][0][s2][lane][0];
                bf16x8 pa1 = *(const bf16x8*)&pt_f[buf][1][s2][lane][0];
                a0 = __builtin_amdgcn_mfma_f32_32x32x16_bf16(pa0, vf[i][kc], a0, 0, 0, 0);
                a1 = __builtin_amdgcn_mfma_f32_32x32x16_bf16(pa1, vf[i][kc], a1, 0, 0, 0);
            }
        __builtin_amdgcn_s_setprio(0);
    };

    // prologue
    bf16x8 kh0 = kload(kt0 + 2 * pp + sc, 0), kh1 = kload(kt0 + 2 * pp + sc, 1);
    {
        f32x16 s = smma(kh0, kh1);
        sfin(s, pp);
    }
    kh0 = kload(kt0 + 2 * (2 + pp) + sc, 0);
    kh1 = kload(kt0 + 2 * (2 + pp) + sc, 1);
    __syncthreads();

    for (int j = 0; j < 16; ++j) {
        f32x16 s;
        if (j < 15) s = smma(kh0, kh1);

        bf16x8 vfa[2][2];
        #pragma unroll
        for (int i = 0; i < 2; ++i)
            #pragma unroll
            for (int kc = 0; kc < 2; ++kc)
                vfa[i][kc] = vload(kt0 + 4 * j + i, kc);

        if (j < 14) {
            const int mtsn = 2 * j + 4 + pp;
            kh0 = kload(kt0 + 2 * mtsn + sc, 0);
            kh1 = kload(kt0 + 2 * mtsn + sc, 1);
        }
        if (j < 15) sfin(s, (2 * j + 2 + pp) & 3);

        bf16x8 vfb[2][2];
        #pragma unroll
        for (int i = 0; i < 2; ++i)
            #pragma unroll
            for (int kc = 0; kc < 2; ++kc)
                vfb[i][kc] = vload(kt0 + 4 * j + 2 + i, kc);

        pvblock(2 * j, vfa);
        pvblock(2 * j + 1, vfb);
        __syncthreads();
    }

    // ---- epilogue: own partials ----
    float dtot = dacc + __shfl_xor(dacc, 32);   // fold h halves (same n)
    if (lane < 32) dwave[w][l31] = dtot;
    __syncthreads();
    if (w < 2 && lane < 32) {
        float dsum = dwave[w][l31] + dwave[w + 2][l31]
                   + dwave[w + 4][l31] + dwave[w + 6][l31];
        dls[32 * w + l31] = dsum;
        dpart[((size_t)(ksp * BS + b)) * NPIX + n0 + 32 * w + l31] = dsum;
    }

    size_t obase = (((size_t)(ksp * BS + b)) * NI + 32 * w + l31) * NPIX + n0;
    #pragma unroll
    for (int rq = 0; rq < 4; ++rq) {
        int nn = 8 * rq + 4 * h;
        __align__(8) __bf16 t0[4], t1[4];
        #pragma unroll
        for (int i = 0; i < 4; ++i) {
            t0[i] = (__bf16)a0[4 * rq + i];
            t1[i] = (__bf16)a1[4 * rq + i];
        }
        *(uint2*)(Opart + obase + nn)      = *(const uint2*)t0;   // n rows 0-31
        *(uint2*)(Opart + obase + 32 + nn) = *(const uint2*)t1;   // n rows 32-63
    }

    // ---- arrival protocol ----
    __threadfence();       // each thread's partial stores visible device-wide
    __syncthreads();       // all threads fenced
    if (t == 0) who = atomicAdd(&flags[(blockIdx.x & 3) * 64 + blockIdx.y], 1);
    __syncthreads();
    if (who == 0) return;  // first arriver: partials published, done
    __threadfence();       // acquire partner's stores

    // ---- fused combine (second arriver) ----
    const int pk = ksp ^ 1;
    if (t < 64) dls[t] += dpart[((size_t)(pk * BS + b)) * NPIX + n0 + t];

    float* stage = (float*)smem;   // [128][65] f32, aliases pt_f (dead now)
    #pragma unroll 1
    for (int half = 0; half < 2; ++half) {
        if ((w >> 2) == half) {    // waves owning this c-half stage own f32 O
            int cl = 32 * (w & 3) + l31;
            #pragma unroll
            for (int rq = 0; rq < 4; ++rq) {
                int nn = 8 * rq + 4 * h;
                #pragma unroll
                for (int i = 0; i < 4; ++i) {
                    stage[cl * 65 + nn + i]      = a0[4 * rq + i];
                    stage[cl * 65 + 32 + nn + i] = a1[4 * rq + i];
                }
            }
        }
        __syncthreads();
        int n4 = (t & 15) * 4, cb = t >> 4;           // cb 0..31
        #pragma unroll
        for (int p = 0; p < 4; ++p) {
            int cl = cb + 32 * p;
            int c  = 128 * half + cl;
            bf16x4 pp4 = *(const bf16x4*)(Opart +
                (((size_t)(pk * BS + b)) * NI + c) * NPIX + n0 + n4);
            float4 xv = *(const float4*)(x + ((size_t)(b * NI) + c) * NPIX + n0 + n4);
            float g = gamma[c];
            float4 r;
            r.x = g * ((stage[cl * 65 + n4 + 0] + (float)pp4[0]) / dls[n4 + 0]) + xv.x;
            r.y = g * ((stage[cl * 65 + n4 + 1] + (float)pp4[1]) / dls[n4 + 1]) + xv.y;
            r.z = g * ((stage[cl * 65 + n4 + 2] + (float)pp4[2]) / dls[n4 + 2]) + xv.z;
            r.w = g * ((stage[cl * 65 + n4 + 3] + (float)pp4[3]) / dls[n4 + 3]) + xv.w;
            *(float4*)(out + ((size_t)(b * NI) + c) * NPIX + n0 + n4) = r;
        }
        __syncthreads();
    }
}

extern "C" void kernel_launch(void* const* d_in, const int* in_sizes, int n_in,
                              void* d_out, int out_size, void* d_ws, size_t ws_size,
                              hipStream_t stream)
{
    const float* x     = (const float*)d_in[0];
    const float* wq    = (const float*)d_in[1];
    const float* bq    = (const float*)d_in[2];
    const float* wk    = (const float*)d_in[3];
    const float* bk    = (const float*)d_in[4];
    const float* wv    = (const float*)d_in[5];
    const float* bv    = (const float*)d_in[6];
    const float* gamma = (const float*)d_in[7];
    float* out = (float*)d_out;

    const size_t WPK = (size_t)10240 * 8;                      // 81920
    const size_t QPK = (size_t)BS * 128 * 2 * 2 * 2 * 32 * 8;  // 1,048,576
    const size_t KPK = (size_t)BS * 128 * 2 * 2 * 32 * 8;      // 524,288
    const size_t VPK = (size_t)BS * 128 * 2 * 2 * 256 * 8;     // 4,194,304
    const size_t OSZ = (size_t)2 * BS * NI * NPIX;             // 8,388,608
    __bf16* wpk   = (__bf16*)d_ws;
    __bf16* qpk   = wpk + WPK;
    __bf16* kpk   = qpk + QPK;
    __bf16* vpk   = kpk + KPK;
    __bf16* Opart = vpk + VPK;
    float*  dpart = (float*)(Opart + OSZ);
    int*    flags = (int*)(dpart + (size_t)2 * BS * NPIX);

    wconv_pack<<<dim3(40), 256, 0, stream>>>(wq, wk, wv, wpk, flags);
    qkv_mfma<<<dim3(NPIX / 32, BS), 256, 0, stream>>>(x, wpk, bq, bk, bv, qpk, kpk, vpk);
    attn_mfma<<<dim3(8, 64), 512, 0, stream>>>(qpk, kpk, vpk, Opart, dpart,
                                               x, gamma, out, flags);
}

// Round 13
// 146.332 us; speedup vs baseline: 2.4047x; 2.4047x over previous
//
#include <hip/hip_runtime.h>
#include <cstdint>
#include <cstddef>

#define NI   256
#define QKC  32
#define BS   4
#define NPIX 4096   // 64*64
#define LOG2E 1.4426950408889634f

typedef __bf16 bf16x8 __attribute__((ext_vector_type(8)));
typedef __bf16 bf16x4 __attribute__((ext_vector_type(4)));
typedef float  f32x16 __attribute__((ext_vector_type(16)));

__device__ inline f32x16 zero16() {
    f32x16 z;
    #pragma unroll
    for (int i = 0; i < 16; ++i) z[i] = 0.f;
    return z;
}

// ---------------- Kernel 0: W -> fragment-packed bf16 ----------------
__global__ __launch_bounds__(256) void wconv_pack(
    const float* __restrict__ wq, const float* __restrict__ wk,
    const float* __restrict__ wv, __bf16* __restrict__ wpk)
{
    int f = blockIdx.x * 256 + threadIdx.x;          // 0..10239
    int otl = f >> 10, rem = f & 1023;
    int kk = rem >> 6, h = (rem >> 5) & 1, l31 = rem & 31;
    int och = otl * 32 + l31, c0 = kk * 16 + 8 * h;
    const float* src = och < 32 ? wq + och * NI + c0
                     : och < 64 ? wk + (och - 32) * NI + c0
                                : wv + (och - 64) * NI + c0;
    float4 x0 = *(const float4*)src;
    float4 x1 = *(const float4*)(src + 4);
    __align__(16) __bf16 o8[8] = {
        (__bf16)x0.x, (__bf16)x0.y, (__bf16)x0.z, (__bf16)x0.w,
        (__bf16)x1.x, (__bf16)x1.y, (__bf16)x1.z, (__bf16)x1.w};
    *(uint4*)(wpk + (size_t)f * 8) = *(const uint4*)o8;
}

// ---------------- Kernel 1: QKV (round-11 verbatim) ----------
// qpk: [b][kt(128)][kc][h][l31][8]  (single bf16 plane)
// kpk: [b][kt(128)][kc][h][l31][8]
// vpk: [b][kt(128)][kc][hh][c'(256)][8]
__global__ __launch_bounds__(256) void qkv_mfma(
    const float* __restrict__ x, const __bf16* __restrict__ wpk,
    const float* __restrict__ bq, const float* __restrict__ bk,
    const float* __restrict__ bv,
    __bf16* __restrict__ qpk, __bf16* __restrict__ kpk, __bf16* __restrict__ vpk)
{
    __shared__ __align__(16) __bf16 xT[32][264];   // also reused as vT
    __shared__ float bls[320];

    const int t = threadIdx.x, w = t >> 6, lane = t & 63;
    const int l31 = lane & 31, h = lane >> 5;
    const int b = blockIdx.y, n0 = blockIdx.x * 32, kt = blockIdx.x;

    for (int i = t; i < 320; i += 256)
        bls[i] = i < 32 ? bq[i] : i < 64 ? bk[i - 32] : bv[i - 64];

    {   // stage x transposed (32 n x 256 c)
        int n4 = (t & 7) * 4, cb = (t >> 3) * 8;
        float4 xv[8];
        #pragma unroll
        for (int j = 0; j < 8; ++j)
            xv[j] = *(const float4*)(x + ((size_t)(b * NI) + cb + j) * NPIX + n0 + n4);
        #pragma unroll
        for (int i = 0; i < 4; ++i) {
            __align__(16) __bf16 r8[8];
            #pragma unroll
            for (int j = 0; j < 8; ++j) r8[j] = (__bf16)((&xv[j].x)[i]);
            *(uint4*)&xT[n4 + i][cb] = *(const uint4*)r8;
        }
    }
    __syncthreads();

    f32x16 acc[3] = {zero16(), zero16(), zero16()};
    #pragma unroll 4
    for (int kk = 0; kk < 16; ++kk) {
        bf16x8 xf = *(const bf16x8*)&xT[l31][kk * 16 + 8 * h];
        #pragma unroll
        for (int jj = 0; jj < 3; ++jj) {
            int otl = w + 4 * jj;
            if (otl < 10) {
                bf16x8 wf = *(const bf16x8*)(wpk + (size_t)((otl * 16 + kk) * 64 + 32 * h + l31) * 8);
                acc[jj] = __builtin_amdgcn_mfma_f32_32x32x16_bf16(wf, xf, acc[jj], 0, 0, 0);
            }
        }
    }
    __syncthreads();   // xT reads done; reuse as vT

    __bf16 (*vT)[264] = xT;
    #pragma unroll
    for (int jj = 0; jj < 3; ++jj) {
        int otl = w + 4 * jj;
        if (otl >= 2 && otl < 10) {
            #pragma unroll
            for (int qd = 0; qd < 4; ++qd) {
                int c0v = (otl - 2) * 32 + 8 * qd + 4 * h;
                __align__(8) __bf16 q4[4];
                #pragma unroll
                for (int i = 0; i < 4; ++i)
                    q4[i] = (__bf16)(acc[jj][4 * qd + i] + bls[64 + c0v + i]);
                *(uint2*)&vT[l31][c0v] = *(const uint2*)q4;
            }
        }
    }
    #pragma unroll
    for (int jj = 0; jj < 3; ++jj) {
        int otl = w + 4 * jj;
        if (otl == 0) {        // q: scale by log2e, single bf16 plane
            #pragma unroll
            for (int kc = 0; kc < 2; ++kc) {
                __align__(16) __bf16 hi8[8];
                #pragma unroll
                for (int j = 0; j < 8; ++j) {
                    int r = 8 * kc + j;
                    int och = (r & 3) + 8 * (r >> 2) + 4 * h;
                    hi8[j] = (__bf16)((acc[jj][r] + bls[och]) * LOG2E);
                }
                size_t base = ((((size_t)(b * 128 + kt) * 2 + 0) * 2 + kc) * 2 + h) * 32 + l31;
                *(uint4*)(qpk + base * 8) = *(const uint4*)hi8;
            }
        } else if (otl == 1) { // k
            #pragma unroll
            for (int kc = 0; kc < 2; ++kc) {
                __align__(16) __bf16 k8[8];
                #pragma unroll
                for (int j = 0; j < 8; ++j) {
                    int r = 8 * kc + j;
                    int och = (r & 3) + 8 * (r >> 2) + 4 * h;
                    k8[j] = (__bf16)(acc[jj][r] + bls[32 + och]);
                }
                size_t base = (((size_t)(b * 128 + kt) * 2 + kc) * 2 + h) * 32 + l31;
                *(uint4*)(kpk + base * 8) = *(const uint4*)k8;
            }
        }
    }
    __syncthreads();   // vT complete

    #pragma unroll
    for (int kc = 0; kc < 2; ++kc)
        #pragma unroll
        for (int hh = 0; hh < 2; ++hh) {
            __align__(16) __bf16 f8[8];
            #pragma unroll
            for (int j = 0; j < 8; ++j) f8[j] = vT[16 * kc + 8 * hh + j][t];
            size_t base = (((size_t)(b * 128 + kt) * 2 + kc) * 2 + hh) * 256 + t;
            *(uint4*)(vpk + base * 8) = *(const uint4*)f8;
        }
}

// ---------------- Kernel 2: attention, full-key 16-wave block --------------
// grid (4 b, 64 n-tiles) = 256 blocks of 1024 thr (16 waves) = 1 block/CU,
// 16 waves/CU (same residency & per-interval rhythm as round 11). Wave:
// quadrant q=w&3 (sr,sc), parity group g=w>>2. S: group g produces m-tiles
// === g (mod 4) into an 8-deep pt_f rotation (buf = mt&7). PV: waves w<8 take
// even m-tiles, w>=8 odd, chunk = w&7. Softmax d complete in-block -> no
// partials/combine/fences (round-12 lesson: device fences = L2 wipe). The
// f32 accumulator pair per chunk is merged in LDS (aliasing dead pt_f) and
// the final gamma*(O/d)+x is written directly, coalesced.
__global__ __launch_bounds__(1024, 4) void attn_mfma(
    const __bf16* __restrict__ qpk, const __bf16* __restrict__ kpk,
    const __bf16* __restrict__ vpk,
    const float* __restrict__ x, const float* __restrict__ gamma,
    float* __restrict__ out)
{
    // pool: max(pt_f 8*2*4*64*8 bf16 = 65536 B, stage 256*68*4 = 69632 B)
    __shared__ __align__(16) unsigned char smem[69632];
    auto pt_f = reinterpret_cast<__bf16 (*)[2][4][64][8]>(smem);
    __shared__ float dwave[16][32];
    __shared__ float dls[64];

    const int t = threadIdx.x;
    const int b = blockIdx.x;
    const int n0 = blockIdx.y * 64;
    const int w = t >> 6, lane = t & 63, l31 = lane & 31, h = lane >> 5;
    const int q = w & 3, sr = q & 1, sc = q >> 1, g = w >> 2;

    // Q fragments for this wave's S n-half (kc halves, single plane)
    const int qt = 2 * blockIdx.y + sr;
    bf16x8 qf[2];
    #pragma unroll
    for (int kc = 0; kc < 2; ++kc)
        qf[kc] = *(const bf16x8*)(qpk +
            (((((size_t)(b * 128 + qt) * 2 + 0) * 2 + kc) * 2 + h) * 32 + l31) * 8);

    auto kload = [&](int ktile, int kc) {
        return *(const bf16x8*)(kpk +
            ((((size_t)(b * 128 + ktile) * 2 + kc) * 2 + h) * 32 + l31) * 8);
    };
    auto vload = [&](int ktile, int kc) {
        return *(const bf16x8*)(vpk +
            ((((size_t)(b * 128 + ktile) * 2 + kc) * 2 + h) * 256
             + 32 * (w & 7) + l31) * 8);
    };

    f32x16 a0 = zero16(), a1 = zero16();
    float dacc = 0.f;

    auto smma = [&](bf16x8 kh0, bf16x8 kh1) {
        f32x16 s = zero16();
        __builtin_amdgcn_s_setprio(1);
        s = __builtin_amdgcn_mfma_f32_32x32x16_bf16(kh0, qf[0], s, 0, 0, 0);
        s = __builtin_amdgcn_mfma_f32_32x32x16_bf16(kh1, qf[1], s, 0, 0, 0);
        __builtin_amdgcn_s_setprio(0);
        return s;
    };

    auto sfin = [&](const f32x16& s, int buf) {
        unsigned xw[8], xs[8];
        #pragma unroll
        for (int i = 0; i < 8; ++i) {
            float e0 = __builtin_amdgcn_exp2f(s[2 * i]);
            float e1 = __builtin_amdgcn_exp2f(s[2 * i + 1]);
            dacc += e0 + e1;
            __align__(4) __bf16 pr[2] = {(__bf16)e0, (__bf16)e1};
            xw[i] = *(const unsigned*)pr;
        }
        #pragma unroll
        for (int i = 0; i < 8; ++i) xs[i] = __shfl_xor(xw[i], 32);
        const bool hi = (h != 0);
        __align__(16) unsigned f0[4], f1[4];
        f0[0] = hi ? xs[2] : xw[0];  f0[1] = hi ? xs[3] : xw[1];
        f0[2] = hi ? xw[2] : xs[0];  f0[3] = hi ? xw[3] : xs[1];
        f1[0] = hi ? xs[6] : xw[4];  f1[1] = hi ? xs[7] : xw[5];
        f1[2] = hi ? xw[6] : xs[4];  f1[3] = hi ? xw[7] : xs[5];
        *(uint4*)&pt_f[buf][sr][2 * sc + 0][lane][0] = *(const uint4*)f0;
        *(uint4*)&pt_f[buf][sr][2 * sc + 1][lane][0] = *(const uint4*)f1;
    };

    auto pvblock = [&](int mt, const bf16x8 (*vf)[2]) {
        const int buf = mt & 7;
        __builtin_amdgcn_s_setprio(1);
        #pragma unroll
        for (int i = 0; i < 2; ++i)
            #pragma unroll
            for (int kc = 0; kc < 2; ++kc) {
                const int s2 = 2 * i + kc;
                bf16x8 pa0 = *(const bf16x8*)&pt_f[buf][0][s2][lane][0];
                bf16x8 pa1 = *(const bf16x8*)&pt_f[buf][1][s2][lane][0];
                a0 = __builtin_amdgcn_mfma_f32_32x32x16_bf16(pa0, vf[i][kc], a0, 0, 0, 0);
                a1 = __builtin_amdgcn_mfma_f32_32x32x16_bf16(pa1, vf[i][kc], a1, 0, 0, 0);
            }
        __builtin_amdgcn_s_setprio(0);
    };

    // prologue: every group g produces S(m-tile g) -> buf g; prefetch g+4
    bf16x8 kh0 = kload(2 * g + sc, 0), kh1 = kload(2 * g + sc, 1);
    {
        f32x16 s = smma(kh0, kh1);
        sfin(s, g);
    }
    kh0 = kload(2 * (4 + g) + sc, 0);
    kh1 = kload(2 * (4 + g) + sc, 1);
    __syncthreads();

    // 16 intervals x 4 m-tiles; one barrier per interval.
    // PV: wave does m-tiles {4j, 4j+2} (w<8) or {4j+1, 4j+3} (w>=8).
    // S:  group g produces m-tile 4j+4+g (1-interval lookahead).
    for (int j = 0; j < 16; ++j) {
        f32x16 s;
        if (j < 15) s = smma(kh0, kh1);

        const int tb = 4 * j + (w >> 3);
        bf16x8 vfa[2][2];
        #pragma unroll
        for (int i = 0; i < 2; ++i)
            #pragma unroll
            for (int kc = 0; kc < 2; ++kc)
                vfa[i][kc] = vload(2 * tb + i, kc);

        if (j < 14) {
            const int nt = 4 * j + 8 + g;
            kh0 = kload(2 * nt + sc, 0);
            kh1 = kload(2 * nt + sc, 1);
        }
        if (j < 15) sfin(s, (4 * j + 4 + g) & 7);

        bf16x8 vfb[2][2];
        #pragma unroll
        for (int i = 0; i < 2; ++i)
            #pragma unroll
            for (int kc = 0; kc < 2; ++kc)
                vfb[i][kc] = vload(2 * (tb + 2) + i, kc);

        pvblock(tb, vfa);
        pvblock(tb + 2, vfb);
        __syncthreads();
    }

    // ---- epilogue (in-block, no fences) ----
    float dtot = dacc + __shfl_xor(dacc, 32);   // fold h halves (same n)
    if (lane < 32) dwave[w][l31] = dtot;
    __syncthreads();                            // pt_f dead; dwave ready

    float* stage = (float*)smem;                // [256][68] f32, aliases pt_f
    if (t < 64) {                               // complete d per n-row
        float ds = 0.f;
        #pragma unroll
        for (int k = 0; k < 8; ++k) ds += dwave[2 * k + (t >> 5)][t & 31];
        dls[t] = ds;
    }
    if (w < 8) {                                // even-tile partials -> stage
        float* sc_ = stage + (32 * (w & 7) + l31) * 68;
        #pragma unroll
        for (int rq = 0; rq < 4; ++rq) {
            int nn = 8 * rq + 4 * h;
            #pragma unroll
            for (int i = 0; i < 4; ++i) {
                sc_[nn + i]      = a0[4 * rq + i];
                sc_[32 + nn + i] = a1[4 * rq + i];
            }
        }
    }
    __syncthreads();
    if (w >= 8) {                               // odd-tile partials += stage
        float* sc_ = stage + (32 * (w & 7) + l31) * 68;
        #pragma unroll
        for (int rq = 0; rq < 4; ++rq) {
            int nn = 8 * rq + 4 * h;
            #pragma unroll
            for (int i = 0; i < 4; ++i) {
                sc_[nn + i]      += a0[4 * rq + i];
                sc_[32 + nn + i] += a1[4 * rq + i];
            }
        }
    }
    __syncthreads();

    // final: r = gamma*(O/d) + x, n-major coalesced float4
    const int n4 = (t & 15) * 4, c0 = t >> 4;   // c0 0..63
    #pragma unroll
    for (int p = 0; p < 4; ++p) {
        const int c = c0 + 64 * p;
        const float gm = gamma[c];
        size_t xb = ((size_t)(b * NI) + c) * NPIX + n0 + n4;
        float4 xv = *(const float4*)(x + xb);
        const float* sc_ = stage + c * 68 + n4;
        float4 r;
        r.x = gm * (sc_[0] / dls[n4 + 0]) + xv.x;
        r.y = gm * (sc_[1] / dls[n4 + 1]) + xv.y;
        r.z = gm * (sc_[2] / dls[n4 + 2]) + xv.z;
        r.w = gm * (sc_[3] / dls[n4 + 3]) + xv.w;
        *(float4*)(out + xb) = r;
    }
}

extern "C" void kernel_launch(void* const* d_in, const int* in_sizes, int n_in,
                              void* d_out, int out_size, void* d_ws, size_t ws_size,
                              hipStream_t stream)
{
    const float* x     = (const float*)d_in[0];
    const float* wq    = (const float*)d_in[1];
    const float* bq    = (const float*)d_in[2];
    const float* wk    = (const float*)d_in[3];
    const float* bk    = (const float*)d_in[4];
    const float* wv    = (const float*)d_in[5];
    const float* bv    = (const float*)d_in[6];
    const float* gamma = (const float*)d_in[7];
    float* out = (float*)d_out;

    const size_t WPK = (size_t)10240 * 8;                      // 81920
    const size_t QPK = (size_t)BS * 128 * 2 * 2 * 2 * 32 * 8;  // 1,048,576
    const size_t KPK = (size_t)BS * 128 * 2 * 2 * 32 * 8;      // 524,288
    __bf16* wpk   = (__bf16*)d_ws;
    __bf16* qpk   = wpk + WPK;
    __bf16* kpk   = qpk + QPK;
    __bf16* vpk   = kpk + KPK;

    wconv_pack<<<dim3(40), 256, 0, stream>>>(wq, wk, wv, wpk);
    qkv_mfma<<<dim3(NPIX / 32, BS), 256, 0, stream>>>(x, wpk, bq, bk, bv, qpk, kpk, vpk);
    attn_mfma<<<dim3(4, 64), 1024, 0, stream>>>(qpk, kpk, vpk, x, gamma, out);
}